// Round 1
// baseline (732.134 us; speedup 1.0000x reference)
//
#include <hip/hip_runtime.h>
#include <math.h>

#define FIN 128
#define D1  256
#define D2  128
#define KCL 32

// ---------------- degree counting ----------------
__global__ void k_degrees(const int* __restrict__ edges, int E,
                          int* __restrict__ deg_in, int* __restrict__ deg_out) {
    int e = blockIdx.x * blockDim.x + threadIdx.x;
    if (e < E) {
        int r = edges[e];        // source
        int c = edges[E + e];    // target
        atomicAdd(&deg_out[r], 1);
        atomicAdd(&deg_in[c], 1);
    }
}

__global__ void k_dinv(const int* __restrict__ deg_in, const int* __restrict__ deg_out,
                       float* __restrict__ dinv1, float* __restrict__ dinv2, int N) {
    int i = blockIdx.x * blockDim.x + threadIdx.x;
    if (i < N) {
        dinv1[i] = rsqrtf((float)(deg_in[i] + 1));   // +1 self loop, always > 0
        int d2 = deg_out[i];
        dinv2[i] = (d2 > 0) ? rsqrtf((float)d2) : 0.0f;
    }
}

// ---------------- exclusive scan (two arrays, one block each) ----------------
__global__ __launch_bounds__(1024) void k_scan(const int* __restrict__ deg_a, int* __restrict__ ptr_a,
                                               const int* __restrict__ deg_b, int* __restrict__ ptr_b,
                                               int N) {
    const int* deg = (blockIdx.x == 0) ? deg_a : deg_b;
    int* ptr       = (blockIdx.x == 0) ? ptr_a : ptr_b;
    __shared__ int sm[1024];
    int t = threadIdx.x;
    int chunk = (N + 1023) >> 10;
    int lo = t * chunk, hi = min(lo + chunk, N);
    int s = 0;
    for (int i = lo; i < hi; i++) s += deg[i];
    sm[t] = s;
    __syncthreads();
    for (int st = 1; st < 1024; st <<= 1) {
        int v = (t >= st) ? sm[t - st] : 0;
        __syncthreads();
        sm[t] += v;
        __syncthreads();
    }
    int run = sm[t] - s;  // exclusive base
    for (int i = lo; i < hi; i++) { ptr[i] = run; run += deg[i]; }
    if (t == 0) ptr[N] = sm[1023];
}

// ---------------- CSR fill ----------------
__global__ void k_fill(const int* __restrict__ edges, int E,
                       const int* __restrict__ col_ptr, const int* __restrict__ row_ptr,
                       int* __restrict__ cur_in, int* __restrict__ cur_out,
                       int* __restrict__ col_idx, int* __restrict__ row_idx) {
    int e = blockIdx.x * blockDim.x + threadIdx.x;
    if (e < E) {
        int r = edges[e], c = edges[E + e];
        int p = col_ptr[c] + atomicAdd(&cur_in[c], 1);
        col_idx[p] = r;                 // in-edges of c: list of sources
        int q = row_ptr[r] + atomicAdd(&cur_out[r], 1);
        row_idx[q] = c;                 // out-edges of r: list of targets
    }
}

// ---------------- tiled fp32 GEMM: C[N,NC] = op(A[N,KTOT] @ B[KTOT,NC]) ----------------
// MODE 0: C = rowscale[i] * (A@B)          (bias unused)
// MODE 1: C = tanh(A@B + bias[c])          (rowscale unused)
template <int KTOT, int NC, int MODE>
__global__ __launch_bounds__(256) void k_gemm(const float* __restrict__ A, const float* __restrict__ B,
                                              const float* __restrict__ bias,
                                              const float* __restrict__ rowscale,
                                              float* __restrict__ C, int N) {
    constexpr int JJ = NC / 32;
    __shared__ float As[32][33];   // [k][node], padded
    __shared__ float Bs[32][NC];   // [k][col]
    int t = threadIdx.x;
    int tc = t & 31;   // col lane
    int tn = t >> 5;   // node group (0..7), owns nodes tn*4..tn*4+3
    int bn = blockIdx.x * 32;
    float acc[4][JJ];
#pragma unroll
    for (int j = 0; j < 4; j++)
#pragma unroll
        for (int jj = 0; jj < JJ; jj++) acc[j][jj] = 0.f;

    for (int k0 = 0; k0 < KTOT; k0 += 32) {
#pragma unroll
        for (int p = 0; p < 4; p++) {
            int nn = p * 8 + tn;
            int node = bn + nn;
            As[tc][nn] = (node < N) ? A[(long)node * KTOT + k0 + tc] : 0.f;
        }
#pragma unroll
        for (int p = 0; p < NC / 32; p++) {
            int idx = p * 256 + t;
            int k = idx / (NC / 4);
            int c4 = (idx % (NC / 4)) * 4;
            *(float4*)&Bs[k][c4] = *(const float4*)&B[(long)(k0 + k) * NC + c4];
        }
        __syncthreads();
#pragma unroll
        for (int k = 0; k < 32; k++) {
            float a0 = As[k][tn * 4 + 0], a1 = As[k][tn * 4 + 1];
            float a2 = As[k][tn * 4 + 2], a3 = As[k][tn * 4 + 3];
#pragma unroll
            for (int jj = 0; jj < JJ; jj++) {
                float b = Bs[k][tc + 32 * jj];
                acc[0][jj] += a0 * b;
                acc[1][jj] += a1 * b;
                acc[2][jj] += a2 * b;
                acc[3][jj] += a3 * b;
            }
        }
        __syncthreads();
    }
#pragma unroll
    for (int j = 0; j < 4; j++) {
        int node = bn + tn * 4 + j;
        if (node < N) {
            float rs = (MODE == 0) ? rowscale[node] : 0.f;
#pragma unroll
            for (int jj = 0; jj < JJ; jj++) {
                int c = tc + 32 * jj;
                float v = acc[j][jj];
                if (MODE == 0) v *= rs;
                else           v = tanhf(v + bias[c]);
                C[(long)node * NC + c] = v;
            }
        }
    }
}

// ---------------- GCN aggregation: H[i] = dinv1[i]*(y[i] + sum_{src in in(i)} y[src]) + b1 ----------------
__global__ __launch_bounds__(256) void k_aggH(const float* __restrict__ y,
                                              const int* __restrict__ col_ptr, const int* __restrict__ col_idx,
                                              const float* __restrict__ dinv1, const float* __restrict__ b1,
                                              float* __restrict__ H, int N) {
    int i = blockIdx.x;
    int t = threadIdx.x;
    int lo = col_ptr[i], hi = col_ptr[i + 1];
    float acc = y[(long)i * D1 + t];   // self loop term (y already scaled by dinv1[src])
    __shared__ int idx[256];
    for (int e0 = lo; e0 < hi; e0 += 256) {
        int cnt = min(256, hi - e0);
        if (t < cnt) idx[t] = col_idx[e0 + t];
        __syncthreads();
        for (int j = 0; j < cnt; j++) acc += y[(long)idx[j] * D1 + t];
        __syncthreads();
    }
    H[(long)i * D1 + t] = dinv1[i] * acc + b1[t];
}

// ---------------- fc2 + softmax + z = dinv2*S ----------------
__global__ __launch_bounds__(256) void k_mlp2(const float* __restrict__ ab, const float* __restrict__ W2,
                                              const float* __restrict__ b2, const float* __restrict__ dinv2,
                                              float* __restrict__ Sm, float* __restrict__ z, int N) {
    __shared__ float Ws[D2 * KCL];
    __shared__ float ar[8][132];   // padded: groups hit distinct banks
    int t = threadIdx.x;
    for (int i = t; i < D2 * KCL; i += 256) Ws[i] = W2[i];
    int g = t >> 5, l = t & 31;
    for (int i0 = blockIdx.x * 8; i0 < N; i0 += gridDim.x * 8) {
        int m = min(8, N - i0);
        __syncthreads();   // protects ar reuse + first-iter Ws readiness
        for (int idx = t; idx < m * 128; idx += 256) ar[idx >> 7][idx & 127] = ab[(long)i0 * 128 + idx];
        __syncthreads();
        if (g < m) {
            int node = i0 + g;
            float logit = b2[l];
#pragma unroll 16
            for (int k = 0; k < 128; k++) logit += ar[g][k] * Ws[k * 32 + l];
            float mx = logit;
#pragma unroll
            for (int mask = 16; mask >= 1; mask >>= 1) mx = fmaxf(mx, __shfl_xor(mx, mask, 32));
            float ex = __expf(logit - mx);
            float sum = ex;
#pragma unroll
            for (int mask = 16; mask >= 1; mask >>= 1) sum += __shfl_xor(sum, mask, 32);
            float sv = ex / sum;
            Sm[(long)node * KCL + l] = sv;
            z[(long)node * KCL + l] = dinv2[node] * sv;
        }
    }
}

// ---------------- LS[i] = S[i] - dinv2[i] * sum_{c in out(i)} z[c] ----------------
__global__ __launch_bounds__(256) void k_LS(const float* __restrict__ Sm, const float* __restrict__ z,
                                            const int* __restrict__ row_ptr, const int* __restrict__ row_idx,
                                            const float* __restrict__ dinv2,
                                            float* __restrict__ LS, int N) {
    int g = threadIdx.x >> 5;
    int l = threadIdx.x & 31;
    int i = blockIdx.x * 8 + g;
    if (i >= N) return;
    int lo = row_ptr[i], hi = row_ptr[i + 1];
    float acc = 0.f;
    for (int e = lo; e < hi; e++) {
        int c = row_idx[e];
        acc += z[(long)c * KCL + l];
    }
    LS[(long)i * KCL + l] = Sm[(long)i * KCL + l] - dinv2[i] * acc;
}

// ---------------- column sum of H (for graph_embedding shortcut) ----------------
__global__ void k_colsum(const float* __restrict__ H, float* __restrict__ colsum, int N) {
    int t = threadIdx.x;
    float acc = 0.f;
    for (int i = blockIdx.x; i < N; i += gridDim.x) acc += H[(long)i * D1 + t];
    atomicAdd(&colsum[t], acc);
}

// ---------------- new_adj = S^T @ LS  (32x32) ----------------
__global__ __launch_bounds__(256) void k_newadj(const float* __restrict__ S, const float* __restrict__ LS,
                                                float* __restrict__ newadj, int N) {
    __shared__ float Ss[8][32], Ls[8][32];
    int t = threadIdx.x;
    int l = t & 31, k0 = t >> 5;  // thread owns (k0 + 8j, l), j=0..3
    float acc[4] = {0.f, 0.f, 0.f, 0.f};
    for (int i0 = blockIdx.x * 8; i0 < N; i0 += gridDim.x * 8) {
        int m = min(8, N - i0);
        if (t < m * 32) {
            Ss[t >> 5][t & 31] = S[(long)i0 * KCL + t];
            Ls[t >> 5][t & 31] = LS[(long)i0 * KCL + t];
        }
        __syncthreads();
        for (int n = 0; n < m; n++) {
            float lv = Ls[n][l];
#pragma unroll
            for (int j = 0; j < 4; j++) acc[j] += Ss[n][k0 + 8 * j] * lv;
        }
        __syncthreads();
    }
#pragma unroll
    for (int j = 0; j < 4; j++) atomicAdd(&newadj[(k0 + 8 * j) * 32 + l], acc[j]);
}

// ---------------- final: pos_penalty + output write ----------------
__global__ void k_final(const float* __restrict__ newadj, const float* __restrict__ colsum,
                        float* __restrict__ out) {
    __shared__ float nd[32];
    int t = threadIdx.x;
    if (t < 32) {
        float rs = 0.f;
        for (int l = 0; l < 32; l++) rs += fabsf(newadj[t * 32 + l]);
        nd[t] = newadj[t * 32 + t] / fmaxf(rs, 1e-12f);
    }
    __syncthreads();
    out[t] = colsum[t] * (1.0f / 32.0f);
    if (t == 0) {
        float p = 0.f;
        for (int j = 0; j < 32; j++) {
            float d = nd[j];
            p += 31.0f * d * d + (d - 1.0f) * (d - 1.0f);
        }
        out[256] = p / 1024.0f;
    }
}

extern "C" void kernel_launch(void* const* d_in, const int* in_sizes, int n_in,
                              void* d_out, int out_size, void* d_ws, size_t ws_size,
                              hipStream_t stream) {
    const float* X     = (const float*)d_in[0];
    const int*   edges = (const int*)d_in[1];
    const float* W1    = (const float*)d_in[2];
    const float* b1    = (const float*)d_in[3];
    const float* fc1_W = (const float*)d_in[4];
    const float* fc1_b = (const float*)d_in[5];
    const float* fc2_W = (const float*)d_in[6];
    const float* fc2_b = (const float*)d_in[7];
    float* out = (float*)d_out;

    int N = in_sizes[0] / FIN;
    int E = in_sizes[1] / 2;

    char* w = (char*)d_ws;
    auto carve = [&](size_t bytes) -> void* {
        void* p = (void*)w;
        w += (bytes + 255) & ~(size_t)255;
        return p;
    };
    float* y      = (float*)carve((size_t)N * D1 * 4);   // dinv1[i] * (X@W1)[i]; later aliased
    float* Hm     = (float*)carve((size_t)N * D1 * 4);
    float* Sm     = (float*)carve((size_t)N * KCL * 4);
    float* zm     = (float*)carve((size_t)N * KCL * 4);
    float* dinv1  = (float*)carve((size_t)N * 4);
    float* dinv2  = (float*)carve((size_t)N * 4);
    int*   degs   = (int*)carve((size_t)4 * N * 4);      // deg_in|deg_out|cur_in|cur_out
    int* deg_in = degs, *deg_out = degs + N, *cur_in = degs + 2 * N, *cur_out = degs + 3 * N;
    int* col_ptr  = (int*)carve((size_t)(N + 1) * 4);
    int* row_ptr  = (int*)carve((size_t)(N + 1) * 4);
    int* col_idx  = (int*)carve((size_t)E * 4);
    int* row_idx  = (int*)carve((size_t)E * 4);
    float* accum  = (float*)carve((size_t)(1024 + 256) * 4);
    float* newadj = accum;
    float* colsum = accum + 1024;
    float* abst = y;   // alias: y dead after k_aggH
    float* LSm  = y;   // alias: abst dead after k_mlp2

    hipMemsetAsync(degs, 0, (size_t)4 * N * 4, stream);
    hipMemsetAsync(accum, 0, (size_t)(1024 + 256) * 4, stream);

    k_degrees<<<(E + 255) / 256, 256, 0, stream>>>(edges, E, deg_in, deg_out);
    k_dinv<<<(N + 255) / 256, 256, 0, stream>>>(deg_in, deg_out, dinv1, dinv2, N);
    k_scan<<<2, 1024, 0, stream>>>(deg_in, col_ptr, deg_out, row_ptr, N);
    k_fill<<<(E + 255) / 256, 256, 0, stream>>>(edges, E, col_ptr, row_ptr, cur_in, cur_out, col_idx, row_idx);
    k_gemm<FIN, D1, 0><<<(N + 31) / 32, 256, 0, stream>>>(X, W1, nullptr, dinv1, y, N);
    k_aggH<<<N, 256, 0, stream>>>(y, col_ptr, col_idx, dinv1, b1, Hm, N);
    k_gemm<D1, D2, 1><<<(N + 31) / 32, 256, 0, stream>>>(Hm, fc1_W, fc1_b, nullptr, abst, N);
    k_mlp2<<<2048, 256, 0, stream>>>(abst, fc2_W, fc2_b, dinv2, Sm, zm, N);
    k_LS<<<(N + 7) / 8, 256, 0, stream>>>(Sm, zm, row_ptr, row_idx, dinv2, LSm, N);
    k_colsum<<<256, 256, 0, stream>>>(Hm, colsum, N);
    k_newadj<<<256, 256, 0, stream>>>(Sm, LSm, newadj, N);
    k_final<<<1, 256, 0, stream>>>(newadj, colsum, out);
}

// Round 2
// 606.810 us; speedup vs baseline: 1.2065x; 1.2065x over previous
//
#include <hip/hip_runtime.h>
#include <math.h>

#define FIN 128
#define D1  256
#define D2  128
#define KCL 32

typedef __attribute__((ext_vector_type(8))) short short8;
typedef __attribute__((ext_vector_type(4))) float floatx4;

__device__ __forceinline__ ushort f2bf(float f) {
    unsigned u = __float_as_uint(f);
    unsigned r = (u + 0x7fffu + ((u >> 16) & 1u)) >> 16;
    return (ushort)r;
}
__device__ __forceinline__ float bf2f(ushort h) {
    return __uint_as_float(((unsigned)h) << 16);
}

// ---------------- degree counting ----------------
__global__ void k_degrees(const int* __restrict__ edges, int E,
                          int* __restrict__ deg_in, int* __restrict__ deg_out) {
    int e = blockIdx.x * blockDim.x + threadIdx.x;
    if (e < E) {
        int r = edges[e];        // source
        int c = edges[E + e];    // target
        atomicAdd(&deg_out[r], 1);
        atomicAdd(&deg_in[c], 1);
    }
}

__global__ void k_dinv(const int* __restrict__ deg_in, const int* __restrict__ deg_out,
                       float* __restrict__ dinv1, float* __restrict__ dinv2, int N) {
    int i = blockIdx.x * blockDim.x + threadIdx.x;
    if (i < N) {
        dinv1[i] = rsqrtf((float)(deg_in[i] + 1));   // +1 self loop, always > 0
        int d2 = deg_out[i];
        dinv2[i] = (d2 > 0) ? rsqrtf((float)d2) : 0.0f;
    }
}

// ---------------- exclusive scan (two arrays, one block each) ----------------
__global__ __launch_bounds__(1024) void k_scan(const int* __restrict__ deg_a, int* __restrict__ ptr_a,
                                               const int* __restrict__ deg_b, int* __restrict__ ptr_b,
                                               int N) {
    const int* deg = (blockIdx.x == 0) ? deg_a : deg_b;
    int* ptr       = (blockIdx.x == 0) ? ptr_a : ptr_b;
    __shared__ int sm[1024];
    int t = threadIdx.x;
    int chunk = (N + 1023) >> 10;
    int lo = t * chunk, hi = min(lo + chunk, N);
    int s = 0;
    for (int i = lo; i < hi; i++) s += deg[i];
    sm[t] = s;
    __syncthreads();
    for (int st = 1; st < 1024; st <<= 1) {
        int v = (t >= st) ? sm[t - st] : 0;
        __syncthreads();
        sm[t] += v;
        __syncthreads();
    }
    int run = sm[t] - s;  // exclusive base
    for (int i = lo; i < hi; i++) { ptr[i] = run; run += deg[i]; }
    if (t == 0) ptr[N] = sm[1023];
}

// ---------------- CSR fill (ushort indices: N < 65536) ----------------
__global__ void k_fill(const int* __restrict__ edges, int E,
                       const int* __restrict__ col_ptr, const int* __restrict__ row_ptr,
                       int* __restrict__ cur_in, int* __restrict__ cur_out,
                       ushort* __restrict__ col_idx, ushort* __restrict__ row_idx) {
    int e = blockIdx.x * blockDim.x + threadIdx.x;
    if (e < E) {
        int r = edges[e], c = edges[E + e];
        int p = col_ptr[c] + atomicAdd(&cur_in[c], 1);
        col_idx[p] = (ushort)r;         // in-edges of c: list of sources
        int q = row_ptr[r] + atomicAdd(&cur_out[r], 1);
        row_idx[q] = (ushort)c;         // out-edges of r: list of targets
    }
}

// ---------------- casts ----------------
// fp32 -> bf16, packed 2 at a time
__global__ void k_cast(const float* __restrict__ src, unsigned* __restrict__ dst, long n2) {
    long i = (long)blockIdx.x * blockDim.x + threadIdx.x;
    if (i < n2) {
        float2 v = ((const float2*)src)[i];
        dst[i] = (unsigned)f2bf(v.x) | ((unsigned)f2bf(v.y) << 16);
    }
}

// fp32 [K][Nc] -> bf16 transposed [Nc][K]
__global__ void k_tcast(const float* __restrict__ src, ushort* __restrict__ dst, int K, int Nc) {
    int idx = blockIdx.x * blockDim.x + threadIdx.x;
    if (idx < K * Nc) {
        int k = idx / Nc, n = idx % Nc;
        dst[n * K + k] = f2bf(src[idx]);
    }
}

// ---------------- bf16 MFMA GEMM: C[N,NC] = op(A[N,KTOT] @ W[KTOT,NC]) ----------------
// A: bf16 row-major [N][KTOT]; Bt: bf16 transposed weights [NC][KTOT].
// MODE 0: C(bf16) = rowscale[i] * (A@W)
// MODE 1: C(fp32) = tanh(A@W + bias[c])
// Block: 256 threads = 4 waves; each wave computes 16 rows x NC cols via 16x16x32 MFMA.
// B panel in LDS, XOR-swizzled 16B chunks (conflict-free, no padding, 64KB max).
template <int KTOT, int NC, int MODE>
__global__ __launch_bounds__(256) void k_gemm_mfma(
    const ushort* __restrict__ A, const ushort* __restrict__ Bt,
    const float* __restrict__ bias, const float* __restrict__ rowscale,
    void* __restrict__ Cout, int N)
{
    constexpr int NT = NC / 16;            // MFMA tiles along N per wave
    __shared__ ushort Bs[NC * KTOT];
    int t = threadIdx.x;
    // stage Bt -> LDS with XOR swizzle on 16B chunks
    constexpr int CPR = KTOT / 8;          // chunks per row
    for (int idx = t; idx < NC * CPR; idx += 256) {
        int n = idx / CPR, c = idx % CPR;
        int cs = c ^ (n & 15);
        *(short8*)&Bs[n * KTOT + cs * 8] = *(const short8*)&Bt[(long)n * KTOT + c * 8];
    }
    __syncthreads();

    int wave = t >> 6, lane = t & 63;
    int quad = lane >> 4, l15 = lane & 15;
    int arow = blockIdx.x * 64 + wave * 16 + l15;
    long aoff_row = (long)min(arow, N - 1) * KTOT;

    floatx4 acc[NT];
#pragma unroll
    for (int tt = 0; tt < NT; tt++) acc[tt] = {0.f, 0.f, 0.f, 0.f};

    for (int k0 = 0; k0 < KTOT; k0 += 32) {
        short8 af = *(const short8*)&A[aoff_row + k0 + quad * 8];
#pragma unroll
        for (int tt = 0; tt < NT; tt++) {
            int n = tt * 16 + l15;
            int cix = ((k0 >> 3) + quad) ^ (n & 15);
            short8 bf = *(const short8*)&Bs[n * KTOT + cix * 8];
            acc[tt] = __builtin_amdgcn_mfma_f32_16x16x32_bf16(af, bf, acc[tt], 0, 0, 0);
        }
    }

    int rbase = blockIdx.x * 64 + wave * 16 + quad * 4;
#pragma unroll
    for (int r = 0; r < 4; r++) {
        int rowi = rbase + r;
        if (rowi < N) {
            float rs = (MODE == 0) ? rowscale[rowi] : 0.f;
#pragma unroll
            for (int tt = 0; tt < NT; tt++) {
                int c = tt * 16 + l15;
                float v = acc[tt][r];
                if (MODE == 0) ((ushort*)Cout)[(long)rowi * NC + c] = f2bf(v * rs);
                else           ((float*)Cout)[(long)rowi * NC + c] = tanhf(v + bias[c]);
            }
        }
    }
}

// ---------------- GCN aggregation (bf16 y -> bf16 H) ----------------
// H[i] = dinv1[i]*(y[i] + sum_{src in in(i)} y[src]) + b1
// 128 threads, thread t owns column pair (2t, 2t+1) packed in one uint.
__global__ __launch_bounds__(128) void k_aggH(const unsigned* __restrict__ y2,
                                              const int* __restrict__ col_ptr, const ushort* __restrict__ col_idx,
                                              const float* __restrict__ dinv1, const float* __restrict__ b1,
                                              unsigned* __restrict__ H2, int N) {
    int i = blockIdx.x;
    int t = threadIdx.x;
    int lo = col_ptr[i], hi = col_ptr[i + 1];
    unsigned p0 = y2[(long)i * 128 + t];     // self loop term (y pre-scaled by dinv1[src])
    float ax = bf2f((ushort)(p0 & 0xffff));
    float ay = bf2f((ushort)(p0 >> 16));
    __shared__ ushort sidx[256];
    for (int e0 = lo; e0 < hi; e0 += 256) {
        int cnt = min(256, hi - e0);
        if (t < cnt) sidx[t] = col_idx[e0 + t];
        if (t + 128 < cnt) sidx[t + 128] = col_idx[e0 + t + 128];
        __syncthreads();
        for (int j = 0; j < cnt; j++) {
            unsigned p = y2[(long)sidx[j] * 128 + t];
            ax += bf2f((ushort)(p & 0xffff));
            ay += bf2f((ushort)(p >> 16));
        }
        __syncthreads();
    }
    float d = dinv1[i];
    float hx = d * ax + b1[2 * t];
    float hy = d * ay + b1[2 * t + 1];
    H2[(long)i * 128 + t] = (unsigned)f2bf(hx) | ((unsigned)f2bf(hy) << 16);
}

// ---------------- fc2 + softmax + z = dinv2*S ----------------
__global__ __launch_bounds__(256) void k_mlp2(const float* __restrict__ ab, const float* __restrict__ W2,
                                              const float* __restrict__ b2, const float* __restrict__ dinv2,
                                              float* __restrict__ Sm, float* __restrict__ z, int N) {
    __shared__ float Ws[D2 * KCL];
    __shared__ float ar[8][132];   // padded: groups hit distinct banks
    int t = threadIdx.x;
    for (int i = t; i < D2 * KCL; i += 256) Ws[i] = W2[i];
    int g = t >> 5, l = t & 31;
    for (int i0 = blockIdx.x * 8; i0 < N; i0 += gridDim.x * 8) {
        int m = min(8, N - i0);
        __syncthreads();   // protects ar reuse + first-iter Ws readiness
        for (int idx = t; idx < m * 128; idx += 256) ar[idx >> 7][idx & 127] = ab[(long)i0 * 128 + idx];
        __syncthreads();
        if (g < m) {
            int node = i0 + g;
            float logit = b2[l];
#pragma unroll 16
            for (int k = 0; k < 128; k++) logit += ar[g][k] * Ws[k * 32 + l];
            float mx = logit;
#pragma unroll
            for (int mask = 16; mask >= 1; mask >>= 1) mx = fmaxf(mx, __shfl_xor(mx, mask, 32));
            float ex = __expf(logit - mx);
            float sum = ex;
#pragma unroll
            for (int mask = 16; mask >= 1; mask >>= 1) sum += __shfl_xor(sum, mask, 32);
            float sv = ex / sum;
            Sm[(long)node * KCL + l] = sv;
            z[(long)node * KCL + l] = dinv2[node] * sv;
        }
    }
}

// ---------------- LS[i] = S[i] - dinv2[i] * sum_{c in out(i)} z[c] ----------------
__global__ __launch_bounds__(256) void k_LS(const float* __restrict__ Sm, const float* __restrict__ z,
                                            const int* __restrict__ row_ptr, const ushort* __restrict__ row_idx,
                                            const float* __restrict__ dinv2,
                                            float* __restrict__ LS, int N) {
    int g = threadIdx.x >> 5;
    int l = threadIdx.x & 31;
    int i = blockIdx.x * 8 + g;
    if (i >= N) return;
    int lo = row_ptr[i], hi = row_ptr[i + 1];
    float acc = 0.f;
    for (int e = lo; e < hi; e++) {
        int c = row_idx[e];
        acc += z[(long)c * KCL + l];
    }
    LS[(long)i * KCL + l] = Sm[(long)i * KCL + l] - dinv2[i] * acc;
}

// ---------------- column sum of bf16 H (graph_embedding shortcut) ----------------
__global__ void k_colsum(const ushort* __restrict__ H, float* __restrict__ colsum, int N) {
    int t = threadIdx.x;
    float acc = 0.f;
    for (int i = blockIdx.x; i < N; i += gridDim.x) acc += bf2f(H[(long)i * D1 + t]);
    atomicAdd(&colsum[t], acc);
}

// ---------------- new_adj = S^T @ LS  (32x32) ----------------
__global__ __launch_bounds__(256) void k_newadj(const float* __restrict__ S, const float* __restrict__ LS,
                                                float* __restrict__ newadj, int N) {
    __shared__ float Ss[8][32], Ls[8][32];
    int t = threadIdx.x;
    int l = t & 31, k0 = t >> 5;  // thread owns (k0 + 8j, l), j=0..3
    float acc[4] = {0.f, 0.f, 0.f, 0.f};
    for (int i0 = blockIdx.x * 8; i0 < N; i0 += gridDim.x * 8) {
        int m = min(8, N - i0);
        if (t < m * 32) {
            Ss[t >> 5][t & 31] = S[(long)i0 * KCL + t];
            Ls[t >> 5][t & 31] = LS[(long)i0 * KCL + t];
        }
        __syncthreads();
        for (int n = 0; n < m; n++) {
            float lv = Ls[n][l];
#pragma unroll
            for (int j = 0; j < 4; j++) acc[j] += Ss[n][k0 + 8 * j] * lv;
        }
        __syncthreads();
    }
#pragma unroll
    for (int j = 0; j < 4; j++) atomicAdd(&newadj[(k0 + 8 * j) * 32 + l], acc[j]);
}

// ---------------- final: pos_penalty + output write ----------------
__global__ void k_final(const float* __restrict__ newadj, const float* __restrict__ colsum,
                        float* __restrict__ out) {
    __shared__ float nd[32];
    int t = threadIdx.x;
    if (t < 32) {
        float rs = 0.f;
        for (int l = 0; l < 32; l++) rs += fabsf(newadj[t * 32 + l]);
        nd[t] = newadj[t * 32 + t] / fmaxf(rs, 1e-12f);
    }
    __syncthreads();
    out[t] = colsum[t] * (1.0f / 32.0f);
    if (t == 0) {
        float p = 0.f;
        for (int j = 0; j < 32; j++) {
            float d = nd[j];
            p += 31.0f * d * d + (d - 1.0f) * (d - 1.0f);
        }
        out[256] = p / 1024.0f;
    }
}

extern "C" void kernel_launch(void* const* d_in, const int* in_sizes, int n_in,
                              void* d_out, int out_size, void* d_ws, size_t ws_size,
                              hipStream_t stream) {
    const float* X     = (const float*)d_in[0];
    const int*   edges = (const int*)d_in[1];
    const float* W1    = (const float*)d_in[2];
    const float* b1    = (const float*)d_in[3];
    const float* fc1_W = (const float*)d_in[4];
    const float* fc1_b = (const float*)d_in[5];
    const float* fc2_W = (const float*)d_in[6];
    const float* fc2_b = (const float*)d_in[7];
    float* out = (float*)d_out;

    int N = in_sizes[0] / FIN;
    int E = in_sizes[1] / 2;

    char* w = (char*)d_ws;
    auto carve = [&](size_t bytes) -> void* {
        void* p = (void*)w;
        w += (bytes + 255) & ~(size_t)255;
        return p;
    };
    ushort* ybf   = (ushort*)carve((size_t)N * D1 * 2);   // bf16 y; later aliased by abst(fp32 N*D2)
    ushort* Hbf   = (ushort*)carve((size_t)N * D1 * 2);   // bf16 H
    ushort* Xbf   = (ushort*)carve((size_t)N * FIN * 2);  // bf16 X; later aliased by LSm
    float* Sm     = (float*)carve((size_t)N * KCL * 4);
    float* zm     = (float*)carve((size_t)N * KCL * 4);
    float* dinv1  = (float*)carve((size_t)N * 4);
    float* dinv2  = (float*)carve((size_t)N * 4);
    int*   degs   = (int*)carve((size_t)4 * N * 4);      // deg_in|deg_out|cur_in|cur_out
    int* deg_in = degs, *deg_out = degs + N, *cur_in = degs + 2 * N, *cur_out = degs + 3 * N;
    int* col_ptr  = (int*)carve((size_t)(N + 1) * 4);
    int* row_ptr  = (int*)carve((size_t)(N + 1) * 4);
    ushort* col_idx = (ushort*)carve((size_t)E * 2);
    ushort* row_idx = (ushort*)carve((size_t)E * 2);
    ushort* W1t   = (ushort*)carve((size_t)FIN * D1 * 2);   // [D1][FIN] bf16
    ushort* fc1Wt = (ushort*)carve((size_t)D1 * D2 * 2);    // [D2][D1] bf16
    float* accum  = (float*)carve((size_t)(1024 + 256) * 4);
    float* newadj = accum;
    float* colsum = accum + 1024;
    float* abst = (float*)ybf;   // alias: ybf dead after k_aggH (N*D2*4 == N*D1*2 bytes)
    float* LSm  = (float*)Xbf;   // alias: Xbf dead after gemm1 (N*KCL*4 <= N*FIN*2 bytes)

    hipMemsetAsync(degs, 0, (size_t)4 * N * 4, stream);
    hipMemsetAsync(accum, 0, (size_t)(1024 + 256) * 4, stream);

    k_degrees<<<(E + 255) / 256, 256, 0, stream>>>(edges, E, deg_in, deg_out);
    k_dinv<<<(N + 255) / 256, 256, 0, stream>>>(deg_in, deg_out, dinv1, dinv2, N);
    k_scan<<<2, 1024, 0, stream>>>(deg_in, col_ptr, deg_out, row_ptr, N);
    k_fill<<<(E + 255) / 256, 256, 0, stream>>>(edges, E, col_ptr, row_ptr, cur_in, cur_out, col_idx, row_idx);

    k_cast<<<(int)(((long)N * FIN / 2 + 255) / 256), 256, 0, stream>>>(X, (unsigned*)Xbf, (long)N * FIN / 2);
    k_tcast<<<(FIN * D1 + 255) / 256, 256, 0, stream>>>(W1, W1t, FIN, D1);
    k_tcast<<<(D1 * D2 + 255) / 256, 256, 0, stream>>>(fc1_W, fc1Wt, D1, D2);

    k_gemm_mfma<FIN, D1, 0><<<(N + 63) / 64, 256, 0, stream>>>(Xbf, W1t, nullptr, dinv1, ybf, N);
    k_aggH<<<N, 128, 0, stream>>>((const unsigned*)ybf, col_ptr, col_idx, dinv1, b1, (unsigned*)Hbf, N);
    k_gemm_mfma<D1, D2, 1><<<(N + 63) / 64, 256, 0, stream>>>(Hbf, fc1Wt, fc1_b, nullptr, abst, N);
    k_mlp2<<<2048, 256, 0, stream>>>(abst, fc2_W, fc2_b, dinv2, Sm, zm, N);
    k_LS<<<(N + 7) / 8, 256, 0, stream>>>(Sm, zm, row_ptr, row_idx, dinv2, LSm, N);
    k_colsum<<<256, 256, 0, stream>>>(Hbf, colsum, N);
    k_newadj<<<256, 256, 0, stream>>>(Sm, LSm, newadj, N);
    k_final<<<1, 256, 0, stream>>>(newadj, colsum, out);
}

// Round 3
// 372.356 us; speedup vs baseline: 1.9662x; 1.6297x over previous
//
#include <hip/hip_runtime.h>
#include <math.h>

#define FIN 128
#define D1  256
#define D2  128
#define KCL 32
#define CAP 8192          // max edges per 256-node bin (avg ~4082, +60 sigma headroom)

typedef __attribute__((ext_vector_type(8))) short short8;
typedef __attribute__((ext_vector_type(4))) float floatx4;

__device__ __forceinline__ ushort f2bf(float f) {
    unsigned u = __float_as_uint(f);
    unsigned r = (u + 0x7fffu + ((u >> 16) & 1u)) >> 16;
    return (ushort)r;
}
__device__ __forceinline__ float bf2f(ushort h) {
    return __uint_as_float(((unsigned)h) << 16);
}

// ---------------- P1: bin-scatter edges (dir 0: by dst, dir 1: by src) ----------------
// One global atomic per (block,bin) instead of per edge: kills the EA atomic-RMW storm.
__global__ __launch_bounds__(256) void k_p1(const int* __restrict__ edges, int E, int NBIN,
                                            int* __restrict__ gcnt, unsigned* __restrict__ binbuf) {
    int dir = blockIdx.y;
    __shared__ int h[256], base[256], cur[256];
    int t = threadIdx.x;
    h[t] = 0;
    __syncthreads();
    int chunk = (E + gridDim.x - 1) / gridDim.x;
    int lo = blockIdx.x * chunk, hi = min(lo + chunk, E);
    const int* keys = dir ? edges : edges + E;   // dir0 key = dst, dir1 key = src
    for (int e = lo + t; e < hi; e += 256) atomicAdd(&h[keys[e] >> 8], 1);
    __syncthreads();
    if (t < NBIN) { base[t] = atomicAdd(&gcnt[dir * NBIN + t], h[t]); }
    cur[t] = 0;
    __syncthreads();
    unsigned* bb = binbuf + (size_t)dir * NBIN * CAP;
    for (int e = lo + t; e < hi; e += 256) {
        int r = edges[e], c = edges[E + e];
        int key = dir ? r : c;
        unsigned payload = dir ? ((unsigned)c | ((unsigned)(r & 255) << 16))
                               : ((unsigned)r | ((unsigned)(c & 255) << 16));
        int b = key >> 8;
        int pos = base[b] + atomicAdd(&cur[b], 1);
        if (pos < CAP) bb[(size_t)b * CAP + pos] = payload;
    }
}

// ---------------- P2: per-bin CSR build + degrees + dinv ----------------
// Block = (bin, dir). All global writes contiguous & block-exclusive.
__global__ __launch_bounds__(256) void k_p2(const unsigned* __restrict__ binbuf, const int* __restrict__ gcnt,
                                            int N, int E, int NBIN,
                                            int* __restrict__ col_ptr, int* __restrict__ row_ptr,
                                            ushort* __restrict__ col_idx, ushort* __restrict__ row_idx,
                                            float* __restrict__ dinv1, float* __restrict__ dinv2) {
    int d = blockIdx.y, b = blockIdx.x, t = threadIdx.x;
    __shared__ int sc[256], h[256], hx[256], cur[256];
    // exclusive scan of bin totals -> global CSR base for this bin
    sc[t] = (t < NBIN) ? gcnt[d * NBIN + t] : 0;
    __syncthreads();
    for (int st = 1; st < 256; st <<= 1) {
        int u = (t >= st) ? sc[t - st] : 0;
        __syncthreads();
        sc[t] += u;
        __syncthreads();
    }
    int cnt_b = gcnt[d * NBIN + b];
    int binbase = sc[b] - cnt_b;
    h[t] = 0;
    __syncthreads();
    const unsigned* bb = binbuf + ((size_t)d * NBIN + b) * CAP;
    int m = min(cnt_b, CAP);
    for (int i = t; i < m; i += 256) atomicAdd(&h[bb[i] >> 16], 1);
    __syncthreads();
    int hv = h[t];
    hx[t] = hv;
    __syncthreads();
    for (int st = 1; st < 256; st <<= 1) {
        int u = (t >= st) ? hx[t - st] : 0;
        __syncthreads();
        hx[t] += u;
        __syncthreads();
    }
    int excl = hx[t] - hv;
    int node = b * 256 + t;
    if (node < N) {
        if (d == 0) {
            dinv1[node] = rsqrtf((float)hv + 1.0f);   // +1 self loop, always > 0
            col_ptr[node] = binbase + excl;
            if (node == N - 1) col_ptr[N] = E;
        } else {
            dinv2[node] = hv ? rsqrtf((float)hv) : 0.0f;
            row_ptr[node] = binbase + excl;
            if (node == N - 1) row_ptr[N] = E;
        }
    }
    hx[t] = excl;   // each thread touches only its own slot; sync below guards readers
    cur[t] = 0;
    __syncthreads();
    ushort* oidx = d ? row_idx : col_idx;
    for (int i = t; i < m; i += 256) {
        unsigned p = bb[i];
        int nl = p >> 16;
        int rk = atomicAdd(&cur[nl], 1);
        oidx[binbase + hx[nl] + rk] = (ushort)(p & 0xffff);
    }
}

// ---------------- weight transposes -> bf16 (both are 32768 elements) ----------------
__global__ void k_tcast2(const float* __restrict__ W1, const float* __restrict__ fc1W,
                         ushort* __restrict__ W1t, ushort* __restrict__ fc1Wt) {
    int idx = blockIdx.x * blockDim.x + threadIdx.x;
    if (idx < FIN * D1) {
        int k = idx / D1, n = idx % D1;
        W1t[n * FIN + k] = f2bf(W1[idx]);
        int k2 = idx / D2, n2 = idx % D2;
        fc1Wt[n2 * D1 + k2] = f2bf(fc1W[idx]);
    }
}

// ---------------- bf16 MFMA GEMM: C[N,NC] = op(A[N,KTOT] @ W[KTOT,NC]) ----------------
// A: row-major [N][KTOT] (fp32 if AFP32, else bf16); Bt: bf16 transposed weights [NC][KTOT].
// MODE 0: C(bf16) = rowscale[i] * (A@W)
// MODE 1: C(fp32) = tanh(A@W + bias[c])
template <int KTOT, int NC, int MODE, bool AFP32>
__global__ __launch_bounds__(256) void k_gemm_mfma(
    const void* __restrict__ A, const ushort* __restrict__ Bt,
    const float* __restrict__ bias, const float* __restrict__ rowscale,
    void* __restrict__ Cout, int N)
{
    constexpr int NT = NC / 16;            // MFMA tiles along N per wave
    __shared__ ushort Bs[NC * KTOT];
    int t = threadIdx.x;
    constexpr int CPR = KTOT / 8;          // 16B chunks per row
    for (int idx = t; idx < NC * CPR; idx += 256) {
        int n = idx / CPR, c = idx % CPR;
        int cs = c ^ (n & 15);             // XOR swizzle: conflict-free ds_read_b128
        *(short8*)&Bs[n * KTOT + cs * 8] = *(const short8*)&Bt[(long)n * KTOT + c * 8];
    }
    __syncthreads();

    int wave = t >> 6, lane = t & 63;
    int quad = lane >> 4, l15 = lane & 15;
    int arow = blockIdx.x * 64 + wave * 16 + l15;
    long aoff_row = (long)min(arow, N - 1) * KTOT;

    floatx4 acc[NT];
#pragma unroll
    for (int tt = 0; tt < NT; tt++) acc[tt] = {0.f, 0.f, 0.f, 0.f};

    for (int k0 = 0; k0 < KTOT; k0 += 32) {
        short8 af;
        if constexpr (AFP32) {
            const float* Ap = (const float*)A + aoff_row + k0 + quad * 8;
            float4 f0 = *(const float4*)Ap;
            float4 f1 = *(const float4*)(Ap + 4);
            af[0] = (short)f2bf(f0.x); af[1] = (short)f2bf(f0.y);
            af[2] = (short)f2bf(f0.z); af[3] = (short)f2bf(f0.w);
            af[4] = (short)f2bf(f1.x); af[5] = (short)f2bf(f1.y);
            af[6] = (short)f2bf(f1.z); af[7] = (short)f2bf(f1.w);
        } else {
            af = *(const short8*)((const ushort*)A + aoff_row + k0 + quad * 8);
        }
#pragma unroll
        for (int tt = 0; tt < NT; tt++) {
            int n = tt * 16 + l15;
            int cix = ((k0 >> 3) + quad) ^ (n & 15);
            short8 bf = *(const short8*)&Bs[n * KTOT + cix * 8];
            acc[tt] = __builtin_amdgcn_mfma_f32_16x16x32_bf16(af, bf, acc[tt], 0, 0, 0);
        }
    }

    int rbase = blockIdx.x * 64 + wave * 16 + quad * 4;
#pragma unroll
    for (int r = 0; r < 4; r++) {
        int rowi = rbase + r;
        if (rowi < N) {
            float rs = (MODE == 0) ? rowscale[rowi] : 0.f;
#pragma unroll
            for (int tt = 0; tt < NT; tt++) {
                int c = tt * 16 + l15;
                float v = acc[tt][r];
                if (MODE == 0) ((ushort*)Cout)[(long)rowi * NC + c] = f2bf(v * rs);
                else           ((float*)Cout)[(long)rowi * NC + c] = tanhf(v + bias[c]);
            }
        }
    }
}

// ---------------- GCN aggregation (bf16 y -> bf16 H) ----------------
__global__ __launch_bounds__(128) void k_aggH(const unsigned* __restrict__ y2,
                                              const int* __restrict__ col_ptr, const ushort* __restrict__ col_idx,
                                              const float* __restrict__ dinv1, const float* __restrict__ b1,
                                              unsigned* __restrict__ H2, int N) {
    int i = blockIdx.x;
    int t = threadIdx.x;
    int lo = col_ptr[i], hi = col_ptr[i + 1];
    unsigned p0 = y2[(long)i * 128 + t];     // self loop (y pre-scaled by dinv1[src])
    float ax = bf2f((ushort)(p0 & 0xffff));
    float ay = bf2f((ushort)(p0 >> 16));
    __shared__ ushort sidx[256];
    for (int e0 = lo; e0 < hi; e0 += 256) {
        int cnt = min(256, hi - e0);
        if (t < cnt) sidx[t] = col_idx[e0 + t];
        if (t + 128 < cnt) sidx[t + 128] = col_idx[e0 + t + 128];
        __syncthreads();
        for (int j = 0; j < cnt; j++) {
            unsigned p = y2[(long)sidx[j] * 128 + t];
            ax += bf2f((ushort)(p & 0xffff));
            ay += bf2f((ushort)(p >> 16));
        }
        __syncthreads();
    }
    float d = dinv1[i];
    float hx = d * ax + b1[2 * t];
    float hy = d * ay + b1[2 * t + 1];
    H2[(long)i * 128 + t] = (unsigned)f2bf(hx) | ((unsigned)f2bf(hy) << 16);
}

// ---------------- fc2 + softmax + z = dinv2*S ----------------
__global__ __launch_bounds__(256) void k_mlp2(const float* __restrict__ ab, const float* __restrict__ W2,
                                              const float* __restrict__ b2, const float* __restrict__ dinv2,
                                              float* __restrict__ Sm, float* __restrict__ z, int N) {
    __shared__ float Ws[D2 * KCL];
    __shared__ float ar[8][132];
    int t = threadIdx.x;
    for (int i = t; i < D2 * KCL; i += 256) Ws[i] = W2[i];
    int g = t >> 5, l = t & 31;
    for (int i0 = blockIdx.x * 8; i0 < N; i0 += gridDim.x * 8) {
        int m = min(8, N - i0);
        __syncthreads();
        for (int idx = t; idx < m * 128; idx += 256) ar[idx >> 7][idx & 127] = ab[(long)i0 * 128 + idx];
        __syncthreads();
        if (g < m) {
            int node = i0 + g;
            float logit = b2[l];
#pragma unroll 16
            for (int k = 0; k < 128; k++) logit += ar[g][k] * Ws[k * 32 + l];
            float mx = logit;
#pragma unroll
            for (int mask = 16; mask >= 1; mask >>= 1) mx = fmaxf(mx, __shfl_xor(mx, mask, 32));
            float ex = __expf(logit - mx);
            float sum = ex;
#pragma unroll
            for (int mask = 16; mask >= 1; mask >>= 1) sum += __shfl_xor(sum, mask, 32);
            float sv = ex / sum;
            Sm[(long)node * KCL + l] = sv;
            z[(long)node * KCL + l] = dinv2[node] * sv;
        }
    }
}

// ---------------- LS[i] = S[i] - dinv2[i] * sum_{c in out(i)} z[c] ----------------
__global__ __launch_bounds__(256) void k_LS(const float* __restrict__ Sm, const float* __restrict__ z,
                                            const int* __restrict__ row_ptr, const ushort* __restrict__ row_idx,
                                            const float* __restrict__ dinv2,
                                            float* __restrict__ LS, int N) {
    int g = threadIdx.x >> 5;
    int l = threadIdx.x & 31;
    int i = blockIdx.x * 8 + g;
    if (i >= N) return;
    int lo = row_ptr[i], hi = row_ptr[i + 1];
    float acc = 0.f;
    for (int e = lo; e < hi; e++) {
        int c = row_idx[e];
        acc += z[(long)c * KCL + l];
    }
    LS[(long)i * KCL + l] = Sm[(long)i * KCL + l] - dinv2[i] * acc;
}

// ---------------- column sum of bf16 H ----------------
__global__ void k_colsum(const ushort* __restrict__ H, float* __restrict__ colsum, int N) {
    int t = threadIdx.x;
    float acc = 0.f;
    for (int i = blockIdx.x; i < N; i += gridDim.x) acc += bf2f(H[(long)i * D1 + t]);
    atomicAdd(&colsum[t], acc);
}

// ---------------- new_adj = S^T @ LS  (32x32) ----------------
__global__ __launch_bounds__(256) void k_newadj(const float* __restrict__ S, const float* __restrict__ LS,
                                                float* __restrict__ newadj, int N) {
    __shared__ float Ss[8][32], Ls[8][32];
    int t = threadIdx.x;
    int l = t & 31, k0 = t >> 5;
    float acc[4] = {0.f, 0.f, 0.f, 0.f};
    for (int i0 = blockIdx.x * 8; i0 < N; i0 += gridDim.x * 8) {
        int m = min(8, N - i0);
        if (t < m * 32) {
            Ss[t >> 5][t & 31] = S[(long)i0 * KCL + t];
            Ls[t >> 5][t & 31] = LS[(long)i0 * KCL + t];
        }
        __syncthreads();
        for (int n = 0; n < m; n++) {
            float lv = Ls[n][l];
#pragma unroll
            for (int j = 0; j < 4; j++) acc[j] += Ss[n][k0 + 8 * j] * lv;
        }
        __syncthreads();
    }
#pragma unroll
    for (int j = 0; j < 4; j++) atomicAdd(&newadj[(k0 + 8 * j) * 32 + l], acc[j]);
}

// ---------------- final: pos_penalty + output write ----------------
__global__ void k_final(const float* __restrict__ newadj, const float* __restrict__ colsum,
                        float* __restrict__ out) {
    __shared__ float nd[32];
    int t = threadIdx.x;
    if (t < 32) {
        float rs = 0.f;
        for (int l = 0; l < 32; l++) rs += fabsf(newadj[t * 32 + l]);
        nd[t] = newadj[t * 32 + t] / fmaxf(rs, 1e-12f);
    }
    __syncthreads();
    out[t] = colsum[t] * (1.0f / 32.0f);
    if (t == 0) {
        float p = 0.f;
        for (int j = 0; j < 32; j++) {
            float d = nd[j];
            p += 31.0f * d * d + (d - 1.0f) * (d - 1.0f);
        }
        out[256] = p / 1024.0f;
    }
}

extern "C" void kernel_launch(void* const* d_in, const int* in_sizes, int n_in,
                              void* d_out, int out_size, void* d_ws, size_t ws_size,
                              hipStream_t stream) {
    const float* X     = (const float*)d_in[0];
    const int*   edges = (const int*)d_in[1];
    const float* W1    = (const float*)d_in[2];
    const float* b1    = (const float*)d_in[3];
    const float* fc1_W = (const float*)d_in[4];
    const float* fc1_b = (const float*)d_in[5];
    const float* fc2_W = (const float*)d_in[6];
    const float* fc2_b = (const float*)d_in[7];
    float* out = (float*)d_out;

    int N = in_sizes[0] / FIN;
    int E = in_sizes[1] / 2;
    int NBIN = (N + 255) >> 8;   // 196 for N=50000 (<=256 required: ushort node ids)

    char* w = (char*)d_ws;
    auto carve = [&](size_t bytes) -> void* {
        void* p = (void*)w;
        w += (bytes + 255) & ~(size_t)255;
        return p;
    };
    ushort* ybf     = (ushort*)carve((size_t)N * D1 * 2);      // bf16 y; aliased by abst later
    ushort* Hbf     = (ushort*)carve((size_t)N * D1 * 2);      // bf16 H
    unsigned* binbuf= (unsigned*)carve((size_t)2 * NBIN * CAP * 4); // dead after P2; aliased by LSm
    float* Sm       = (float*)carve((size_t)N * KCL * 4);
    float* zm       = (float*)carve((size_t)N * KCL * 4);
    float* dinv1    = (float*)carve((size_t)N * 4);
    float* dinv2    = (float*)carve((size_t)N * 4);
    int* col_ptr    = (int*)carve((size_t)(N + 1) * 4);
    int* row_ptr    = (int*)carve((size_t)(N + 1) * 4);
    ushort* col_idx = (ushort*)carve((size_t)E * 2);
    ushort* row_idx = (ushort*)carve((size_t)E * 2);
    ushort* W1t     = (ushort*)carve((size_t)FIN * D1 * 2);    // [D1][FIN] bf16
    ushort* fc1Wt   = (ushort*)carve((size_t)D1 * D2 * 2);     // [D2][D1] bf16
    float* accum    = (float*)carve((size_t)(1024 + 256 + 512) * 4);
    float* newadj   = accum;
    float* colsum   = accum + 1024;
    int*   gcnt     = (int*)(accum + 1024 + 256);              // [2][NBIN]
    float* abst = (float*)ybf;     // alias: ybf dead after k_aggH
    float* LSm  = (float*)binbuf;  // alias: binbuf dead after k_p2

    hipMemsetAsync(accum, 0, (size_t)(1024 + 256 + 512) * 4, stream);

    k_p1<<<dim3(256, 2), 256, 0, stream>>>(edges, E, NBIN, gcnt, binbuf);
    k_p2<<<dim3(NBIN, 2), 256, 0, stream>>>(binbuf, gcnt, N, E, NBIN,
                                            col_ptr, row_ptr, col_idx, row_idx, dinv1, dinv2);
    k_tcast2<<<(FIN * D1 + 255) / 256, 256, 0, stream>>>(W1, fc1_W, W1t, fc1Wt);

    k_gemm_mfma<FIN, D1, 0, true><<<(N + 63) / 64, 256, 0, stream>>>(X, W1t, nullptr, dinv1, ybf, N);
    k_aggH<<<N, 128, 0, stream>>>((const unsigned*)ybf, col_ptr, col_idx, dinv1, b1, (unsigned*)Hbf, N);
    k_gemm_mfma<D1, D2, 1, false><<<(N + 63) / 64, 256, 0, stream>>>(Hbf, fc1Wt, fc1_b, nullptr, abst, N);
    k_mlp2<<<2048, 256, 0, stream>>>(abst, fc2_W, fc2_b, dinv2, Sm, zm, N);
    k_LS<<<(N + 7) / 8, 256, 0, stream>>>(Sm, zm, row_ptr, row_idx, dinv2, LSm, N);
    k_colsum<<<256, 256, 0, stream>>>(Hbf, colsum, N);
    k_newadj<<<256, 256, 0, stream>>>(Sm, LSm, newadj, N);
    k_final<<<1, 256, 0, stream>>>(newadj, colsum, out);
}